// Round 1
// baseline (37999.240 us; speedup 1.0000x reference)
//
#include <hip/hip_runtime.h>

#define NHID 512
#define NXW  128
#define TLEN 16384
#define STEPS (TLEN - NXW)      // 16256
#define GRID 256                // 8x grid; only bid%8==0 persist (XCD co-location harvest)
#define B    512                // 8 waves per WG
#define RPW  16                 // hidden rows owned per WG
#define RSLOTS 4                // sync ring depth (16 KB; depth-2 provably safe, 4 = margin)

#define FOR4(M)  M(0) M(1) M(2) M(3)
#define FOR16(M) M(0) M(1) M(2) M(3) M(4) M(5) M(6) M(7) \
                 M(8) M(9) M(10) M(11) M(12) M(13) M(14) M(15)

__device__ __forceinline__ float sigmoid_f(float v) { return 1.f / (1.f + __expf(-v)); }
__device__ __forceinline__ float tanh_f(float v)    { return 1.f - 2.f / (1.f + __expf(2.f * v)); }

// sc0 = L1-bypass, serviced coherently at this XCD's L2 (gfx940+ flag; old glc).
// Used for the intra-XCD fast path. The IC (agent-scope atomic) path remains as
// a correctness anchor for any consumer whose producer is not L2-visible.
__device__ __forceinline__ unsigned long long ld_ring_l2(const unsigned long long* p) {
    unsigned long long v;
    asm volatile("global_load_dwordx2 %0, %1, off sc0\n\ts_waitcnt vmcnt(0)"
                 : "=v"(v) : "v"(p) : "memory");
    return v;
}
__device__ __forceinline__ void st_ring_l2(unsigned long long* p, unsigned long long v) {
    asm volatile("global_store_dwordx2 %0, %1, off sc0" :: "v"(p), "v"(v) : "memory");
}

// ---------------------------------------------------------------------------
// R3 skeleton + hot-ring sync, now XCD-localized.
//
// Launch 256 WGs; only bid%8==0 persist (blockIdx->XCD is round-robin %8 on
// MI355X, so the 32 participants land on the 32 CUs of ONE XCD). Participant
// slot g = bid>>3 owns rows [g*16, g*16+16).
//
// Ring word = {tag:32 | h_bits:32}; consumer of step t polls slot (t-1)&3
// until tag == t-1. Harness 0xAA poison = tag 0xAAAAAAAA, never a valid t.
// Slot reuse race-free: observing all tags t-1 proves every WG passed the
// step-(t-1) barrier, i.e. finished reading every tag <= t-2, so overwriting
// slot t&3 (holding tag t-4) is safe.
//
// Fast path: producers store the ring word with sc0 (lands in the shared
// XCD-local L2) AND shadow-store agent-scope to the IC. Consumers poll with
// sc0 loads; if a consumer's word doesn't validate within 8192 spins (wrong
// placement or wrong sc0 model), it STICKILY degrades to IC atomic polling —
// graceful fallback to exactly the previous kernel's (verified) behavior.
// h_hist gets plain stores purely for the mu epilogue (kernel-boundary
// release fence makes them visible to mu_kernel).
// ---------------------------------------------------------------------------
__launch_bounds__(B, 2)
__global__ void lstm_persistent(
    const float* x,
    const float* Wf, const float* Uf, const float* bf,
    const float* Wi, const float* Ui, const float* bi,
    const float* Wo, const float* Uo, const float* bo,
    const float* Wc, const float* Uc, const float* bc,
    unsigned long long* ring,     // [RSLOTS][NHID] packed {tag,h}
    float* h_hist)                // [STEPS][NHID] for mu only
{
    if (blockIdx.x & 7) return;          // keep one WG per CU-slot of a single XCD
    const int g = blockIdx.x >> 3;       // participant slot 0..31

    __shared__ float x_win[256];                    // x ring: refill every 128 steps
    __shared__ __align__(16) float h_buf[8][64];    // per-wave h-slice staging
    __shared__ float partials[2][B];                // double-buffered

    const int tid = threadIdx.x;
    const int w   = tid >> 6;            // wave = k-slice 0..7
    const int l   = tid & 63;            // output 0..63
    const int q   = l >> 4;              // gate 0=f 1=i 2=o 3=c
    const int row = g * RPW + (l & 15);

    const float* Utab[4] = {Uf, Ui, Uo, Uc};
    const float* Wtab[4] = {Wf, Wi, Wo, Wc};
    const float* Btab[4] = {bf, bi, bo, bc};

    // load + pin weights: 64 U floats + 16 W floats per thread (R3-proven)
    const float4* Up = (const float4*)(Utab[q] + (size_t)row * NHID + w * 64);
    #define DECLU(i) float4 u##i = Up[i];
    FOR16(DECLU)
    const float4* Wp = (const float4*)(Wtab[q] + row * NXW + w * 16);
    #define DECLW(i) float4 wv##i = Wp[i];
    FOR4(DECLW)
    #define PIN(r) asm volatile("" : "+v"(r.x), "+v"(r.y), "+v"(r.z), "+v"(r.w));
    #define PINU(i) PIN(u##i)
    FOR16(PINU)
    #define PINW(i) PIN(wv##i)
    FOR4(PINW)

    float bias = 0.f, c_prev = 0.f;
    if (w == 0) bias = Btab[q][row];

    h_buf[w][l] = 0.f;                   // h[-1] = 0 (own wave reads only)

    bool lfast = true;                   // optimistic L2 polling; sticky degrade

    for (int t = 0; t < STEPS; ++t) {
        if ((t & 127) == 0) {            // x window refill (covers x[t..t+255])
            __syncthreads();
            if (tid < 256) {
                int gi = t + tid;
                x_win[tid] = (gi < TLEN) ? x[gi] : 0.f;
            }
            __syncthreads();
        }

        // issue the FIRST ring sample before the x-projection so the x FMAs
        // overlap the load latency instead of delaying the poll
        const unsigned want = (unsigned)(t - 1);
        const unsigned long long* src =
            ring + ((size_t)((t - 1) & (RSLOTS - 1)) << 9) + (w * 64 + l);
        unsigned long long vv = 0;
        if (t > 0)
            vv = lfast ? ld_ring_l2(src)
                       : __hip_atomic_load(src, __ATOMIC_RELAXED, __HIP_MEMORY_SCOPE_AGENT);

        // x-projection partial (independent of h), 2 accumulators
        float xa0 = 0.f, xa1 = 0.f;
        {
            const int xb = (t & 127) + w * 16;
            #define XF(i, A) A += wv##i.x * x_win[xb + 4*i]     \
                                + wv##i.y * x_win[xb + 4*i + 1] \
                                + wv##i.z * x_win[xb + 4*i + 2] \
                                + wv##i.w * x_win[xb + 4*i + 3];
            XF(0, xa0) XF(1, xa1) XF(2, xa0) XF(3, xa1)
        }
        const float xacc = xa0 + xa1;

        // poll own 8B ring word of h[t-1]: tag-validated
        if (t > 0) {
            if (lfast) {
                int guard = 0;
                while ((unsigned)(vv >> 32) != want) {
                    if (++guard == 8192) { lfast = false; break; }  // sticky degrade
                    vv = ld_ring_l2(src);
                }
            }
            if (!lfast) {
                while ((unsigned)(vv >> 32) != want)
                    vv = __hip_atomic_load(src, __ATOMIC_RELAXED, __HIP_MEMORY_SCOPE_AGENT);
            }
            h_buf[w][l] = __uint_as_float((unsigned)vv);
        }

        // U @ h slice: 64 FMA, 4 independent accumulators (break the dep chain)
        float ac0 = xacc, ac1 = 0.f, ac2 = 0.f, ac3 = 0.f;
        const float4* hb4 = (const float4*)h_buf[w];
        #define UF(i, A) { float4 hv = hb4[i];                    \
                           A += u##i.x * hv.x + u##i.y * hv.y     \
                              + u##i.z * hv.z + u##i.w * hv.w; }
        UF(0,  ac0) UF(1,  ac1) UF(2,  ac2) UF(3,  ac3)
        UF(4,  ac0) UF(5,  ac1) UF(6,  ac2) UF(7,  ac3)
        UF(8,  ac0) UF(9,  ac1) UF(10, ac2) UF(11, ac3)
        UF(12, ac0) UF(13, ac1) UF(14, ac2) UF(15, ac3)
        const float acc = (ac0 + ac1) + (ac2 + ac3);

        partials[t & 1][tid] = acc;
        __syncthreads();                 // the ONE per-step barrier

        // wave-0 tail: reduce 8 k-slices, activate, combine, publish to ring
        if (w == 0) {
            const float* p = partials[t & 1];
            float r0 = p[64  + l] + p[128 + l];
            float r1 = p[192 + l] + p[256 + l];
            float r2 = p[320 + l] + p[384 + l];
            float r3 = p[448 + l];
            float pre = ((acc + bias) + r0) + ((r1 + r2) + r3);
            float a = (l < 48) ? sigmoid_f(pre) : tanh_f(pre);   // f,i,o / g
            float ai = __shfl(a, l + 16, 64);
            float ao = __shfl(a, l + 32, 64);
            float ag = __shfl(a, l + 48, 64);
            if (l < 16) {
                float c = a * c_prev + ai * ag;
                c_prev = c;
                float h = ao * tanh_f(c);
                unsigned long long pv =
                    ((unsigned long long)(unsigned)t << 32)
                    | (unsigned long long)__float_as_uint(h);
                unsigned long long* dst =
                    ring + ((size_t)(t & (RSLOTS - 1)) << 9) + row;
                st_ring_l2(dst, pv);                 // XCD-local L2 (fast consumers)
                __hip_atomic_store(dst, pv,          // IC shadow (degraded consumers)
                    __ATOMIC_RELAXED, __HIP_MEMORY_SCOPE_AGENT);
                h_hist[(size_t)t * NHID + row] = h;  // mu only, off-path
            }
        }
    }
}

// ---------------------------------------------------------------------------
// epilogue: mu[t] = Ahy . h_hist[t] + by   (one wave per t)
// ---------------------------------------------------------------------------
__global__ void mu_kernel(const float* __restrict__ h_hist,
                          const float* __restrict__ Ahy,
                          const float* __restrict__ by,
                          float* __restrict__ outp, int steps)
{
    int wave = threadIdx.x >> 6;
    int lane = threadIdx.x & 63;
    int t = blockIdx.x * 4 + wave;
    if (t >= steps) return;
    const float* h = h_hist + (size_t)t * NHID;
    float p = 0.f;
    #pragma unroll
    for (int e = 0; e < 8; e++)
        p += Ahy[e * 64 + lane] * h[e * 64 + lane];
    #pragma unroll
    for (int off = 32; off; off >>= 1) p += __shfl_down(p, off, 64);
    if (lane == 0) outp[t] = p + by[0];
}

// ---------------------------------------------------------------------------
extern "C" void kernel_launch(void* const* d_in, const int* in_sizes, int n_in,
                              void* d_out, int out_size, void* d_ws, size_t ws_size,
                              hipStream_t stream)
{
    const float* x  = (const float*)d_in[0];
    const float* Wf = (const float*)d_in[1];
    const float* Uf = (const float*)d_in[2];
    const float* bf = (const float*)d_in[3];
    const float* Wi = (const float*)d_in[4];
    const float* Ui = (const float*)d_in[5];
    const float* bi = (const float*)d_in[6];
    const float* Wo = (const float*)d_in[7];
    const float* Uo = (const float*)d_in[8];
    const float* bo = (const float*)d_in[9];
    const float* Wc = (const float*)d_in[10];
    const float* Uc = (const float*)d_in[11];
    const float* bc = (const float*)d_in[12];
    const float* Ahy = (const float*)d_in[13];
    const float* by  = (const float*)d_in[14];

    unsigned long long* ring = (unsigned long long*)d_ws;        // 16 KB
    float* h_hist = (float*)((char*)d_ws + RSLOTS * NHID * 8);   // ~33.3 MB

    lstm_persistent<<<GRID, B, 0, stream>>>(x, Wf, Uf, bf, Wi, Ui, bi,
                                            Wo, Uo, bo, Wc, Uc, bc, ring, h_hist);
    int muBlocks = (STEPS + 3) / 4;
    mu_kernel<<<muBlocks, 256, 0, stream>>>(h_hist, Ahy, by, (float*)d_out, STEPS);
}

// Round 2
// 28111.407 us; speedup vs baseline: 1.3517x; 1.3517x over previous
//
#include <hip/hip_runtime.h>

#define NHID 512
#define NXW  128
#define TLEN 16384
#define STEPS (TLEN - NXW)      // 16256
#define G    32                 // persistent workgroups
#define B    512                // 8 waves per WG
#define RPW  16                 // hidden rows owned per WG
#define RSLOTS 8                // sync ring depth (32 KB -> stays IC/L2-hot)
#define XWIN 640                // 512-slot circular x window + 127 mirror

#define FOR4(M)  M(0) M(1) M(2) M(3)
#define FOR16(M) M(0) M(1) M(2) M(3) M(4) M(5) M(6) M(7) \
                 M(8) M(9) M(10) M(11) M(12) M(13) M(14) M(15)

__device__ __forceinline__ float sigmoid_f(float v) { return 1.f / (1.f + __expf(-v)); }
__device__ __forceinline__ float tanh_f(float v)    { return 1.f - 2.f / (1.f + __expf(2.f * v)); }

#define AL(p) __hip_atomic_load((p), __ATOMIC_RELAXED, __HIP_MEMORY_SCOPE_AGENT)
#define SLP() asm volatile("s_sleep 4")

// ---------------------------------------------------------------------------
// R0 skeleton (verified 25.6 ms) + phase-spread pipelined polling + barrier-
// free background x refill.
//
// WG g owns rows [g*16, g*16+16). 8 waves = 8 k-slices of 64.
// Lane l = output (gate q=l>>4, row g*16+(l&15)); wave w polls h-slice
// [w*64, w*64+64) of the ring.
//
// Ring word = {tag:32 | h_bits:32}; consumer of step t polls slot (t-1)&7
// until tag == t-1. Harness 0xAA poison = tag 0xAAAAAAAA, never a valid t.
// Slot reuse race-free: observing all tags t-1 proves every WG completed
// step t-1, i.e. finished reading every tag <= t-2, so overwriting slot t&7
// (holding tag t-8) is safe.
//
// Polling: a single load->wait->check loop samples the IC once per round
// trip (~700-900 cy), so the expected observation delay is ~1.5 RTT. Here we
// keep 3 agent-scope loads in flight, primed ~256 cy apart (s_sleep 4); the
// check-oldest/reissue loop preserves each slot's phase, so the IC is
// sampled ~every RTT/3. Tag-in-word makes any validated sample THE value
// (the (slot,tag) word is written exactly once), so which sample wins is
// irrelevant to correctness.
//
// x window: 512 live slots + 127-slot mirror, refilled 128 floats at a time
// by wave 7 (slots provably dead: refill offset +256..+383 mod 512 is
// disjoint from the live read span +0..+254). First use of refilled data is
// >=129 per-step barriers later -> no extra barrier needed.
// ---------------------------------------------------------------------------
__launch_bounds__(B, 2)
__global__ void lstm_persistent(
    const float* x,
    const float* Wf, const float* Uf, const float* bf,
    const float* Wi, const float* Ui, const float* bi,
    const float* Wo, const float* Uo, const float* bo,
    const float* Wc, const float* Uc, const float* bc,
    unsigned long long* ring,     // [RSLOTS][NHID] packed {tag,h}
    float* h_hist)                // [STEPS][NHID] for mu only
{
    __shared__ float x_win[XWIN];
    __shared__ __align__(16) float h_buf[8][64];    // per-wave h-slice staging
    __shared__ float partials[2][B];                // double-buffered

    const int tid = threadIdx.x;
    const int g   = blockIdx.x;
    const int w   = tid >> 6;            // wave = k-slice 0..7
    const int l   = tid & 63;            // output 0..63
    const int q   = l >> 4;              // gate 0=f 1=i 2=o 3=c
    const int row = g * RPW + (l & 15);

    const float* Utab[4] = {Uf, Ui, Uo, Uc};
    const float* Wtab[4] = {Wf, Wi, Wo, Wc};
    const float* Btab[4] = {bf, bi, bo, bc};

    // load + pin weights: 64 U floats + 16 W floats per thread (R3-proven)
    const float4* Up = (const float4*)(Utab[q] + (size_t)row * NHID + w * 64);
    #define DECLU(i) float4 u##i = Up[i];
    FOR16(DECLU)
    const float4* Wp = (const float4*)(Wtab[q] + row * NXW + w * 16);
    #define DECLW(i) float4 wv##i = Wp[i];
    FOR4(DECLW)
    #define PIN(r) asm volatile("" : "+v"(r.x), "+v"(r.y), "+v"(r.z), "+v"(r.w));
    #define PINU(i) PIN(u##i)
    FOR16(PINU)
    #define PINW(i) PIN(wv##i)
    FOR4(PINW)

    float bias = 0.f, c_prev = 0.f;
    if (w == 0) bias = Btab[q][row];

    h_buf[w][l] = 0.f;                   // h[-1] = 0 (own wave reads only)

    // prologue: fill x[0..511] (+mirror of first 128)
    {
        float v = x[tid];
        x_win[tid] = v;
        if (tid < XWIN - 512) x_win[512 + tid] = v;
    }
    __syncthreads();

    for (int t = 0; t < STEPS; ++t) {
        // background x refill by wave 7: x[t+256 .. t+383] into dead slots.
        // No barrier: first read of these values is >=129 barriers away.
        if (((t & 127) == 0) && w == 7) {
            int j = t + 256 + (l << 1);
            #pragma unroll
            for (int k2 = 0; k2 < 2; ++k2) {
                int jj = j + k2;
                float v = (jj < TLEN) ? x[jj] : 0.f;
                int s = jj & 511;
                x_win[s] = v;
                if (s < XWIN - 512) x_win[512 + s] = v;
            }
        }

        // issue poll sample 0 before the x-projection (FMAs hide its latency)
        const unsigned want = (unsigned)(t - 1);
        const unsigned long long* src =
            ring + ((size_t)((t - 1) & (RSLOTS - 1)) << 9) + (w * 64 + l);
        unsigned long long a = 0;
        if (t > 0) a = AL(src);

        // x-projection partial (independent of h), 2 accumulators
        float xa0 = 0.f, xa1 = 0.f;
        {
            const int xb = (t & 511) + w * 16;
            #define XF(i, A) A += wv##i.x * x_win[xb + 4*i]     \
                                + wv##i.y * x_win[xb + 4*i + 1] \
                                + wv##i.z * x_win[xb + 4*i + 2] \
                                + wv##i.w * x_win[xb + 4*i + 3];
            XF(0, xa0) XF(1, xa1) XF(2, xa0) XF(3, xa1)
        }
        const float xacc = xa0 + xa1;

        // phase-spread pipelined poll of own 8B ring word of h[t-1]
        if (t > 0) {
            if ((unsigned)(a >> 32) != want) {
                unsigned long long b0 = AL(src); SLP();
                unsigned long long b1 = AL(src); SLP();
                unsigned long long b2 = AL(src);
                int guard = 1 << 20;
                for (;;) {
                    if ((unsigned)(b0 >> 32) == want) { a = b0; break; }
                    b0 = AL(src);
                    if ((unsigned)(b1 >> 32) == want) { a = b1; break; }
                    b1 = AL(src);
                    if ((unsigned)(b2 >> 32) == want) { a = b2; break; }
                    b2 = AL(src);
                    if (--guard == 0) { a = b2; break; }   // safety valve
                }
            }
            h_buf[w][l] = __uint_as_float((unsigned)a);
        }

        // U @ h slice: 64 FMA, 4 independent accumulators
        float ac0 = xacc, ac1 = 0.f, ac2 = 0.f, ac3 = 0.f;
        const float4* hb4 = (const float4*)h_buf[w];
        #define UF(i, A) { float4 hv = hb4[i];                    \
                           A += u##i.x * hv.x + u##i.y * hv.y     \
                              + u##i.z * hv.z + u##i.w * hv.w; }
        UF(0,  ac0) UF(1,  ac1) UF(2,  ac2) UF(3,  ac3)
        UF(4,  ac0) UF(5,  ac1) UF(6,  ac2) UF(7,  ac3)
        UF(8,  ac0) UF(9,  ac1) UF(10, ac2) UF(11, ac3)
        UF(12, ac0) UF(13, ac1) UF(14, ac2) UF(15, ac3)
        const float acc = (ac0 + ac1) + (ac2 + ac3);

        partials[t & 1][tid] = acc;
        __syncthreads();                 // the ONE per-step barrier

        // wave-0 tail: reduce 8 k-slices, activate, combine, publish to ring
        if (w == 0) {
            const float* p = partials[t & 1];
            float r0 = p[64  + l] + p[128 + l];
            float r1 = p[192 + l] + p[256 + l];
            float r2 = p[320 + l] + p[384 + l];
            float r3 = p[448 + l];
            float pre = ((acc + bias) + r0) + ((r1 + r2) + r3);
            float a2 = (l < 48) ? sigmoid_f(pre) : tanh_f(pre);  // f,i,o / g
            float ai = __shfl(a2, l + 16, 64);
            float ao = __shfl(a2, l + 32, 64);
            float ag = __shfl(a2, l + 48, 64);
            if (l < 16) {
                float c = a2 * c_prev + ai * ag;
                c_prev = c;
                float h = ao * tanh_f(c);
                unsigned long long pv =
                    ((unsigned long long)(unsigned)t << 32)
                    | (unsigned long long)__float_as_uint(h);
                __hip_atomic_store(
                    ring + ((size_t)(t & (RSLOTS - 1)) << 9) + row, pv,
                    __ATOMIC_RELAXED, __HIP_MEMORY_SCOPE_AGENT);
                h_hist[(size_t)t * NHID + row] = h;   // mu only, off-path
            }
        }
    }
}

// ---------------------------------------------------------------------------
// epilogue: mu[t] = Ahy . h_hist[t] + by   (one wave per t)
// ---------------------------------------------------------------------------
__global__ void mu_kernel(const float* __restrict__ h_hist,
                          const float* __restrict__ Ahy,
                          const float* __restrict__ by,
                          float* __restrict__ outp, int steps)
{
    int wave = threadIdx.x >> 6;
    int lane = threadIdx.x & 63;
    int t = blockIdx.x * 4 + wave;
    if (t >= steps) return;
    const float* h = h_hist + (size_t)t * NHID;
    float p = 0.f;
    #pragma unroll
    for (int e = 0; e < 8; e++)
        p += Ahy[e * 64 + lane] * h[e * 64 + lane];
    #pragma unroll
    for (int off = 32; off; off >>= 1) p += __shfl_down(p, off, 64);
    if (lane == 0) outp[t] = p + by[0];
}

// ---------------------------------------------------------------------------
extern "C" void kernel_launch(void* const* d_in, const int* in_sizes, int n_in,
                              void* d_out, int out_size, void* d_ws, size_t ws_size,
                              hipStream_t stream)
{
    const float* x  = (const float*)d_in[0];
    const float* Wf = (const float*)d_in[1];
    const float* Uf = (const float*)d_in[2];
    const float* bf = (const float*)d_in[3];
    const float* Wi = (const float*)d_in[4];
    const float* Ui = (const float*)d_in[5];
    const float* bi = (const float*)d_in[6];
    const float* Wo = (const float*)d_in[7];
    const float* Uo = (const float*)d_in[8];
    const float* bo = (const float*)d_in[9];
    const float* Wc = (const float*)d_in[10];
    const float* Uc = (const float*)d_in[11];
    const float* bc = (const float*)d_in[12];
    const float* Ahy = (const float*)d_in[13];
    const float* by  = (const float*)d_in[14];

    unsigned long long* ring = (unsigned long long*)d_ws;        // 32 KB
    float* h_hist = (float*)((char*)d_ws + RSLOTS * NHID * 8);   // ~33.3 MB

    lstm_persistent<<<G, B, 0, stream>>>(x, Wf, Uf, bf, Wi, Ui, bi,
                                         Wo, Uo, bo, Wc, Uc, bc, ring, h_hist);
    int muBlocks = (STEPS + 3) / 4;
    mu_kernel<<<muBlocks, 256, 0, stream>>>(h_hist, Ahy, by, (float*)d_out, STEPS);
}

// Round 3
// 26022.894 us; speedup vs baseline: 1.4602x; 1.0803x over previous
//
#include <hip/hip_runtime.h>

#define NHID 512
#define NXW  128
#define TLEN 16384
#define STEPS (TLEN - NXW)      // 16256
#define G    32                 // persistent workgroups
#define B    512                // 8 waves per WG
#define RPW  16                 // hidden rows owned per WG
#define RSLOTS 8                // sync ring depth (32 KB -> stays IC/L2-hot)

#define FOR4(M)  M(0) M(1) M(2) M(3)
#define FOR16(M) M(0) M(1) M(2) M(3) M(4) M(5) M(6) M(7) \
                 M(8) M(9) M(10) M(11) M(12) M(13) M(14) M(15)

__device__ __forceinline__ float sigmoid_f(float v) { return 1.f / (1.f + __expf(-v)); }
__device__ __forceinline__ float tanh_f(float v)    { return 1.f - 2.f / (1.f + __expf(2.f * v)); }

#define AL(p) __hip_atomic_load((p), __ATOMIC_RELAXED, __HIP_MEMORY_SCOPE_AGENT)

// ~300 cy of dependent FMA issue. Purpose: stagger the issue of poll sample
// b2 relative to b1 so the three in-flight samples observe the IC at ~RTT/3
// phase offsets. Unlike s_sleep (R2's mistake: blocks the wave 64*N cycles
// BEFORE the first check), this occupies only cycles the wave would spend
// vmcnt-stalled anyway, and it is skipped whenever sample 0 validates.
__device__ __forceinline__ void stagger_delay(float& v) {
    #pragma unroll
    for (int i = 0; i < 75; ++i)
        asm volatile("v_fmac_f32 %0, %1, %1" : "+v"(v) : "v"(1.0000001f));
}

// ---------------------------------------------------------------------------
// R0 skeleton (verified 25.6 ms) + sleepless staggered 3-deep polling.
// WG g owns rows [g*16, g*16+16). 8 waves = 8 k-slices of 64.
// Lane l = output (gate q=l>>4, row g*16+(l&15)); wave w polls h-slice
// [w*64, w*64+64) of the ring.
// Ring word = {tag:32 | h_bits:32}; consumer of step t polls slot (t-1)&7
// until tag == t-1. Harness 0xAA poison = tag 0xAAAAAAAA, never a valid t,
// so stale launches can't validate. Slot reuse is race-free: observing all
// tags t-1 proves every WG completed step t-1, i.e. finished reading every
// tag <= t-2, so overwriting slot t&7 (holding tag t-8) is safe.
// The (slot,tag) word is written exactly once, so ANY validated sample is
// THE value — which of the 3 pipelined samples wins is irrelevant.
// h_hist gets plain (non-sync) stores purely for the mu epilogue.
// ---------------------------------------------------------------------------
__launch_bounds__(B, 2)
__global__ void lstm_persistent(
    const float* x,
    const float* Wf, const float* Uf, const float* bf,
    const float* Wi, const float* Ui, const float* bi,
    const float* Wo, const float* Uo, const float* bo,
    const float* Wc, const float* Uc, const float* bc,
    unsigned long long* ring,     // [RSLOTS][NHID] packed {tag,h}
    float* h_hist)                // [STEPS][NHID] for mu only
{
    __shared__ float x_win[256];                    // x ring: refill every 128 steps
    __shared__ __align__(16) float h_buf[8][64];    // per-wave h-slice staging
    __shared__ float partials[2][B];                // double-buffered

    const int tid = threadIdx.x;
    const int g   = blockIdx.x;
    const int w   = tid >> 6;            // wave = k-slice 0..7
    const int l   = tid & 63;            // output 0..63
    const int q   = l >> 4;              // gate 0=f 1=i 2=o 3=c
    const int row = g * RPW + (l & 15);

    const float* Utab[4] = {Uf, Ui, Uo, Uc};
    const float* Wtab[4] = {Wf, Wi, Wo, Wc};
    const float* Btab[4] = {bf, bi, bo, bc};

    // load + pin weights: 64 U floats + 16 W floats per thread (R3-proven)
    const float4* Up = (const float4*)(Utab[q] + (size_t)row * NHID + w * 64);
    #define DECLU(i) float4 u##i = Up[i];
    FOR16(DECLU)
    const float4* Wp = (const float4*)(Wtab[q] + row * NXW + w * 16);
    #define DECLW(i) float4 wv##i = Wp[i];
    FOR4(DECLW)
    #define PIN(r) asm volatile("" : "+v"(r.x), "+v"(r.y), "+v"(r.z), "+v"(r.w));
    #define PINU(i) PIN(u##i)
    FOR16(PINU)
    #define PINW(i) PIN(wv##i)
    FOR4(PINW)

    float bias = 0.f, c_prev = 0.f;
    if (w == 0) bias = Btab[q][row];

    h_buf[w][l] = 0.f;                   // h[-1] = 0 (own wave reads only)

    for (int t = 0; t < STEPS; ++t) {
        if ((t & 127) == 0) {            // x window refill (covers x[t..t+255])
            __syncthreads();
            if (tid < 256) {
                int gi = t + tid;
                x_win[tid] = (gi < TLEN) ? x[gi] : 0.f;
            }
            __syncthreads();
        }

        // issue poll sample 0 before the x-projection (FMAs hide its latency)
        const unsigned want = (unsigned)(t - 1);
        const unsigned long long* src =
            ring + ((size_t)((t - 1) & (RSLOTS - 1)) << 9) + (w * 64 + l);
        unsigned long long vv = 0;
        if (t > 0) vv = AL(src);

        // x-projection partial (independent of h), 2 accumulators.
        // ~150 cy: also the natural stagger between sample 0 and sample b1.
        float xa0 = 0.f, xa1 = 0.f;
        {
            const int xb = (t & 127) + w * 16;
            #define XF(i, A) A += wv##i.x * x_win[xb + 4*i]     \
                                + wv##i.y * x_win[xb + 4*i + 1] \
                                + wv##i.z * x_win[xb + 4*i + 2] \
                                + wv##i.w * x_win[xb + 4*i + 3];
            XF(0, xa0) XF(1, xa1) XF(2, xa0) XF(3, xa1)
        }
        const float xacc = xa0 + xa1;

        // staggered 3-deep pipelined poll of own 8B ring word of h[t-1]
        if (t > 0) {
            if ((unsigned)(vv >> 32) != want) {
                unsigned long long b1 = AL(src);   // issued ~150 cy after vv
                float dly = xacc;
                stagger_delay(dly);                // ~300 cy, wave busy not asleep
                asm volatile("" :: "v"(dly));      // keep chain live (rule #17)
                unsigned long long b2 = AL(src);   // issued ~450 cy after vv
                int guard = 1 << 20;
                for (;;) {
                    if ((unsigned)(vv >> 32) == want) break;
                    vv = AL(src);
                    if ((unsigned)(b1 >> 32) == want) { vv = b1; break; }
                    b1 = AL(src);
                    if ((unsigned)(b2 >> 32) == want) { vv = b2; break; }
                    b2 = AL(src);
                    if (--guard == 0) break;       // safety valve
                }
            }
            h_buf[w][l] = __uint_as_float((unsigned)vv);
        }

        // U @ h slice: 64 FMA, 4 independent accumulators (verified in R1/R2)
        float ac0 = xacc, ac1 = 0.f, ac2 = 0.f, ac3 = 0.f;
        const float4* hb4 = (const float4*)h_buf[w];
        #define UF(i, A) { float4 hv = hb4[i];                    \
                           A += u##i.x * hv.x + u##i.y * hv.y     \
                              + u##i.z * hv.z + u##i.w * hv.w; }
        UF(0,  ac0) UF(1,  ac1) UF(2,  ac2) UF(3,  ac3)
        UF(4,  ac0) UF(5,  ac1) UF(6,  ac2) UF(7,  ac3)
        UF(8,  ac0) UF(9,  ac1) UF(10, ac2) UF(11, ac3)
        UF(12, ac0) UF(13, ac1) UF(14, ac2) UF(15, ac3)
        const float acc = (ac0 + ac1) + (ac2 + ac3);

        partials[t & 1][tid] = acc;
        __syncthreads();                 // the ONE per-step barrier

        // wave-0 tail: reduce 8 k-slices, activate, combine, publish to ring
        if (w == 0) {
            const float* p = partials[t & 1];
            float r0 = p[64  + l] + p[128 + l];
            float r1 = p[192 + l] + p[256 + l];
            float r2 = p[320 + l] + p[384 + l];
            float r3 = p[448 + l];
            float pre = ((acc + bias) + r0) + ((r1 + r2) + r3);
            float a = (l < 48) ? sigmoid_f(pre) : tanh_f(pre);   // f,i,o / g
            float ai = __shfl(a, l + 16, 64);
            float ao = __shfl(a, l + 32, 64);
            float ag = __shfl(a, l + 48, 64);
            if (l < 16) {
                float c = a * c_prev + ai * ag;
                c_prev = c;
                float h = ao * tanh_f(c);
                unsigned long long pv =
                    ((unsigned long long)(unsigned)t << 32)
                    | (unsigned long long)__float_as_uint(h);
                __hip_atomic_store(
                    ring + ((size_t)(t & (RSLOTS - 1)) << 9) + row, pv,
                    __ATOMIC_RELAXED, __HIP_MEMORY_SCOPE_AGENT);
                h_hist[(size_t)t * NHID + row] = h;   // mu only, off-path
            }
        }
    }
}

// ---------------------------------------------------------------------------
// epilogue: mu[t] = Ahy . h_hist[t] + by   (one wave per t)
// ---------------------------------------------------------------------------
__global__ void mu_kernel(const float* __restrict__ h_hist,
                          const float* __restrict__ Ahy,
                          const float* __restrict__ by,
                          float* __restrict__ outp, int steps)
{
    int wave = threadIdx.x >> 6;
    int lane = threadIdx.x & 63;
    int t = blockIdx.x * 4 + wave;
    if (t >= steps) return;
    const float* h = h_hist + (size_t)t * NHID;
    float p = 0.f;
    #pragma unroll
    for (int e = 0; e < 8; e++)
        p += Ahy[e * 64 + lane] * h[e * 64 + lane];
    #pragma unroll
    for (int off = 32; off; off >>= 1) p += __shfl_down(p, off, 64);
    if (lane == 0) outp[t] = p + by[0];
}

// ---------------------------------------------------------------------------
extern "C" void kernel_launch(void* const* d_in, const int* in_sizes, int n_in,
                              void* d_out, int out_size, void* d_ws, size_t ws_size,
                              hipStream_t stream)
{
    const float* x  = (const float*)d_in[0];
    const float* Wf = (const float*)d_in[1];
    const float* Uf = (const float*)d_in[2];
    const float* bf = (const float*)d_in[3];
    const float* Wi = (const float*)d_in[4];
    const float* Ui = (const float*)d_in[5];
    const float* bi = (const float*)d_in[6];
    const float* Wo = (const float*)d_in[7];
    const float* Uo = (const float*)d_in[8];
    const float* bo = (const float*)d_in[9];
    const float* Wc = (const float*)d_in[10];
    const float* Uc = (const float*)d_in[11];
    const float* bc = (const float*)d_in[12];
    const float* Ahy = (const float*)d_in[13];
    const float* by  = (const float*)d_in[14];

    unsigned long long* ring = (unsigned long long*)d_ws;        // 32 KB
    float* h_hist = (float*)((char*)d_ws + RSLOTS * NHID * 8);   // ~33.3 MB

    lstm_persistent<<<G, B, 0, stream>>>(x, Wf, Uf, bf, Wi, Ui, bi,
                                         Wo, Uo, bo, Wc, Uc, bc, ring, h_hist);
    int muBlocks = (STEPS + 3) / 4;
    mu_kernel<<<muBlocks, 256, 0, stream>>>(h_hist, Ahy, by, (float*)d_out, STEPS);
}